// Round 1
// baseline (404.343 us; speedup 1.0000x reference)
//
#include <hip/hip_runtime.h>

// LoRA forward: out = x @ (A @ B * scale)  ==  ((x @ A) * scale) @ B
// x: [4, 2048, 4096] fp32 -> 8192 rows of 4096
// A: [4096, 8] fp32 (row-major, 32 B per row)
// B: [8, 4096] fp32 (row-major)
// out: [8192, 4096] fp32
//
// Memory-bound: read x (128 MiB) + write out (128 MiB); A/B are L2-resident.
// One block per row; 256 threads; each thread handles 4 float4 chunks.

#define DIM   4096
#define RANK  8
#define LORA_SCALE 2.0f
#define BLOCK 256
#define CHUNKS 4   // DIM / 4 (float4) / BLOCK

__global__ __launch_bounds__(BLOCK) void lora_fused_kernel(
    const float* __restrict__ x,
    const float* __restrict__ A,
    const float* __restrict__ B,
    float* __restrict__ out)
{
    const int row = blockIdx.x;
    const int tid = threadIdx.x;
    const float* xr  = x   + (size_t)row * DIM;
    float*       outr = out + (size_t)row * DIM;

    // ---- Phase 1: partial t[r] = sum_i x[i] * A[i][r] ----
    float t[RANK];
#pragma unroll
    for (int r = 0; r < RANK; ++r) t[r] = 0.0f;

#pragma unroll
    for (int k = 0; k < CHUNKS; ++k) {
        const int i4 = tid + BLOCK * k;           // float4 index in row
        const int i  = i4 * 4;                    // element index
        const float4 xv = ((const float4*)xr)[i4];
        const float xe[4] = {xv.x, xv.y, xv.z, xv.w};
#pragma unroll
        for (int j = 0; j < 4; ++j) {
            // A row (i+j): 8 contiguous floats (two dwordx4 loads)
            const float4* arow = (const float4*)(A + (size_t)(i + j) * RANK);
            const float4 a0 = arow[0];
            const float4 a1 = arow[1];
            t[0] += xe[j] * a0.x;
            t[1] += xe[j] * a0.y;
            t[2] += xe[j] * a0.z;
            t[3] += xe[j] * a0.w;
            t[4] += xe[j] * a1.x;
            t[5] += xe[j] * a1.y;
            t[6] += xe[j] * a1.z;
            t[7] += xe[j] * a1.w;
        }
    }

    // ---- Phase 2: block reduction of t[0..7] ----
    // wave-level butterfly (wave = 64 lanes)
#pragma unroll
    for (int r = 0; r < RANK; ++r) {
#pragma unroll
        for (int off = 32; off > 0; off >>= 1) {
            t[r] += __shfl_down(t[r], off, 64);
        }
    }

    __shared__ float red[BLOCK / 64][RANK];
    __shared__ float tf[RANK];
    const int wave = tid >> 6;
    const int lane = tid & 63;
    if (lane == 0) {
#pragma unroll
        for (int r = 0; r < RANK; ++r) red[wave][r] = t[r];
    }
    __syncthreads();
    if (tid < RANK) {
        float s = red[0][tid] + red[1][tid] + red[2][tid] + red[3][tid];
        tf[tid] = s * LORA_SCALE;
    }
    __syncthreads();

    float tv[RANK];
#pragma unroll
    for (int r = 0; r < RANK; ++r) tv[r] = tf[r];

    // ---- Phase 3: out[i] = sum_r tv[r] * B[r][i] ----
#pragma unroll
    for (int k = 0; k < CHUNKS; ++k) {
        const int i4 = tid + BLOCK * k;
        float4 acc = make_float4(0.f, 0.f, 0.f, 0.f);
#pragma unroll
        for (int r = 0; r < RANK; ++r) {
            const float4 bv = ((const float4*)(B + (size_t)r * DIM))[i4];
            acc.x += tv[r] * bv.x;
            acc.y += tv[r] * bv.y;
            acc.z += tv[r] * bv.z;
            acc.w += tv[r] * bv.w;
        }
        ((float4*)outr)[i4] = acc;
    }
}

extern "C" void kernel_launch(void* const* d_in, const int* in_sizes, int n_in,
                              void* d_out, int out_size, void* d_ws, size_t ws_size,
                              hipStream_t stream) {
    const float* x = (const float*)d_in[0];   // [4, 2048, 4096]
    const float* A = (const float*)d_in[1];   // [4096, 8]
    const float* B = (const float*)d_in[2];   // [8, 4096]
    float* out = (float*)d_out;               // [4, 2048, 4096]

    const int rows = in_sizes[0] / DIM;       // 8192
    lora_fused_kernel<<<rows, BLOCK, 0, stream>>>(x, A, B, out);
}

// Round 2
// 242.005 us; speedup vs baseline: 1.6708x; 1.6708x over previous
//
#include <hip/hip_runtime.h>

// LoRA forward: out = x @ (A @ B * scale)  ==  ((x @ A) * scale) @ B
// x: [4, 2048, 4096] fp32 -> 8192 rows of 4096
// A: [4096, 8] fp32 (row-major) -> transposed once to At[8][4096] in ws
// B: [8, 4096] fp32 (row-major)
// out: [8192, 4096] fp32
//
// R1 post-mortem: strided per-element A loads (128 B lane stride) shattered
// coalescing -> latency-bound at 780 GB/s. Fix: transpose A (coalesced
// streams), block 4 rows per block to amortize cached At/B reads
// (L2 traffic 2 GiB -> 512 MiB).

#define DIM    4096
#define DIM4   (DIM / 4)
#define RANK   8
#define LORA_SCALE 2.0f
#define BLOCK  256
#define CHUNK  4      // DIM4 / BLOCK
#define RPB    4      // rows of x per block

// ---- Kernel 1: At[r][i] = A[i][r] (coalesced writes, strided reads; tiny) ----
__global__ __launch_bounds__(BLOCK) void transpose_A_kernel(
    const float* __restrict__ A, float* __restrict__ At)
{
    const int o = blockIdx.x * BLOCK + threadIdx.x;   // 0 .. 8*4096-1
    const int r = o >> 12;                            // 0..7
    const int i = o & (DIM - 1);                      // 0..4095
    At[o] = A[(size_t)i * RANK + r];
}

// ---- Kernel 2: fused ((x@A)*s)@B, 4 rows per block ----
__global__ __launch_bounds__(BLOCK) void lora_fused_kernel(
    const float* __restrict__ x,
    const float* __restrict__ At,
    const float* __restrict__ B,
    float* __restrict__ out)
{
    const int tid  = threadIdx.x;
    const int row0 = blockIdx.x * RPB;
    const float4* x4  = (const float4*)x;
    const float4* At4 = (const float4*)At;
    const float4* B4  = (const float4*)B;
    float4* out4 = (float4*)out;

    // ---- Phase 1: partial acc[m][r] = sum_i x[row0+m][i] * At[r][i] ----
    float acc[RPB][RANK];
#pragma unroll
    for (int m = 0; m < RPB; ++m)
#pragma unroll
        for (int r = 0; r < RANK; ++r) acc[m][r] = 0.0f;

#pragma unroll
    for (int k = 0; k < CHUNK; ++k) {
        const int i4 = tid + BLOCK * k;
        float4 a[RANK];
#pragma unroll
        for (int r = 0; r < RANK; ++r) a[r] = At4[r * DIM4 + i4];
#pragma unroll
        for (int m = 0; m < RPB; ++m) {
            const float4 xv = x4[(size_t)(row0 + m) * DIM4 + i4];
#pragma unroll
            for (int r = 0; r < RANK; ++r) {
                acc[m][r] += xv.x * a[r].x + xv.y * a[r].y
                           + xv.z * a[r].z + xv.w * a[r].w;
            }
        }
    }

    // ---- Phase 2: block reduction of acc[RPB][RANK] ----
#pragma unroll
    for (int m = 0; m < RPB; ++m)
#pragma unroll
        for (int r = 0; r < RANK; ++r)
#pragma unroll
            for (int off = 32; off > 0; off >>= 1)
                acc[m][r] += __shfl_down(acc[m][r], off, 64);

    __shared__ float red[BLOCK / 64][RPB][RANK];
    __shared__ float tf[RPB][RANK];
    const int wave = tid >> 6;
    const int lane = tid & 63;
    if (lane == 0) {
#pragma unroll
        for (int m = 0; m < RPB; ++m)
#pragma unroll
            for (int r = 0; r < RANK; ++r) red[wave][m][r] = acc[m][r];
    }
    __syncthreads();
    if (tid < RPB * RANK) {
        const int m = tid / RANK;
        const int r = tid % RANK;
        tf[m][r] = (red[0][m][r] + red[1][m][r] + red[2][m][r] + red[3][m][r])
                   * LORA_SCALE;
    }
    __syncthreads();

    float tv[RPB][RANK];
#pragma unroll
    for (int m = 0; m < RPB; ++m)
#pragma unroll
        for (int r = 0; r < RANK; ++r) tv[m][r] = tf[m][r];

    // ---- Phase 3: out[row0+m][i] = sum_r tv[m][r] * B[r][i] ----
#pragma unroll
    for (int k = 0; k < CHUNK; ++k) {
        const int i4 = tid + BLOCK * k;
        float4 b[RANK];
#pragma unroll
        for (int r = 0; r < RANK; ++r) b[r] = B4[r * DIM4 + i4];
#pragma unroll
        for (int m = 0; m < RPB; ++m) {
            float4 o = make_float4(0.f, 0.f, 0.f, 0.f);
#pragma unroll
            for (int r = 0; r < RANK; ++r) {
                o.x += tv[m][r] * b[r].x;
                o.y += tv[m][r] * b[r].y;
                o.z += tv[m][r] * b[r].z;
                o.w += tv[m][r] * b[r].w;
            }
            out4[(size_t)(row0 + m) * DIM4 + i4] = o;
        }
    }
}

extern "C" void kernel_launch(void* const* d_in, const int* in_sizes, int n_in,
                              void* d_out, int out_size, void* d_ws, size_t ws_size,
                              hipStream_t stream) {
    const float* x = (const float*)d_in[0];   // [4, 2048, 4096]
    const float* A = (const float*)d_in[1];   // [4096, 8]
    const float* B = (const float*)d_in[2];   // [8, 4096]
    float* out = (float*)d_out;
    float* At  = (float*)d_ws;                // 8*4096 floats = 128 KiB

    const int rows = in_sizes[0] / DIM;       // 8192

    transpose_A_kernel<<<(RANK * DIM) / BLOCK, BLOCK, 0, stream>>>(A, At);
    lora_fused_kernel<<<rows / RPB, BLOCK, 0, stream>>>(x, At, B, out);
}